// Round 8
// baseline (125.374 us; speedup 1.0000x reference)
//
#include <hip/hip_runtime.h>
#include <hip/hip_fp16.h>

#define S_N 16
#define T_N 400
#define F_N 16
#define SF_N 250
#define G_N 4
#define OUT_ROW 100400   // 400 + 250*400

typedef _Float16 f16x8 __attribute__((ext_vector_type(8)));
typedef float    f32x4 __attribute__((ext_vector_type(4)));

union QU { uint4 u; f16x8 v; };

// dynamic LDS: 1600 rows (g*400+t), each padded to 5 uint4 (80 B, data in 4)
#define LDS_U4   8000        // 128,000 B

// ---------------------------------------------------------------------------
// Fully fused kernel. grid 256 = (s, chunk of 6250 samples), block 1024
// threads = 16 waves, 1 block/CU (125 KiB LDS).
// Phase 1: weights -> static LDS (A = Sig^T*W1 folded normalize+layer1).
// Phase 2: q[s] built DIRECTLY into LDS (no global q-table round-trip):
//          q[g][t][k] = sum_{j in grp g} (obs[s,t,j]-mu_j)*A[j][k], fp16.
// Phase 3: threads 0..24 emit this block's 25 unshuffled outputs.
// Phase 4: shuffled eval, one wave = 64 samples, mfma_f32_16x16x32_f16 with
//          A = W2^T; gathers are ds_read_b128 (TA path was the round-2..6
//          46 us wall: 25.6M divergent lane-requests at ~1/cyc/CU).
// ---------------------------------------------------------------------------
__global__ __launch_bounds__(1024, 4) void fused_kernel(
    const float* __restrict__ obs,   // (S,T,F)
    const float* __restrict__ mu,    // (F,1)
    const float* __restrict__ Sig,   // (F,F)
    const int*   __restrict__ perm,  // (SF,G,S,T)
    const float* __restrict__ W1,    // (F,32)
    const float* __restrict__ b1,    // (32,)
    const float* __restrict__ W2,    // (32,16)
    const float* __restrict__ b2,    // (16,)
    const float* __restrict__ W3,    // (16,1)
    const float* __restrict__ b3,    // (1,)
    float* __restrict__ out)         // (S, OUT_ROW) f32
{
    extern __shared__ uint4 smem[];  // 8000 uint4

    __shared__ float sAm[512];       // A[j][k] = sum_i Sig[i][j]*W1[i][k]
    __shared__ float sW2[512];
    __shared__ float sMu[16];
    __shared__ float sB1[32];
    __shared__ float sB2[16];
    __shared__ float sW3[16];
    __shared__ float sB3;

    const int tid   = threadIdx.x;       // 0..1023
    const int s     = blockIdx.x >> 4;
    const int chunk = blockIdx.x & 15;
    const int j0b   = chunk * 6250;      // block's sample range

    // ---- phase 1: weights into LDS ----
    if (tid < 512) {
        const int j = tid >> 5, k = tid & 31;
        float acc = 0.f;
        #pragma unroll
        for (int i = 0; i < 16; ++i)
            acc = fmaf(Sig[i * 16 + j], W1[i * 32 + k], acc);
        sAm[tid] = acc;
    } else {
        sW2[tid - 512] = W2[tid - 512];
    }
    if (tid < 16) sMu[tid] = mu[tid];
    if (tid < 32) sB1[tid] = b1[tid];
    if (tid < 16) sB2[tid] = b2[tid];
    if (tid < 16) sW3[tid] = W3[tid];
    if (tid == 0) sB3 = b3[0];
    __syncthreads();

    // ---- phase 2: build q[s] directly in LDS (fp16, 80B-padded rows) ----
    for (int e = tid; e < 1600; e += 1024) {
        const int t = e >> 2, g = e & 3;   // lanes cover contiguous 64B of obs
        const float4 o = *(const float4*)(obs + ((size_t)s * 400 + t) * 16 + g * 4);
        const float x0 = o.x - sMu[4 * g + 0];
        const float x1 = o.y - sMu[4 * g + 1];
        const float x2 = o.z - sMu[4 * g + 2];
        const float x3 = o.w - sMu[4 * g + 3];
        const float* A0 = sAm + (4 * g + 0) * 32;
        const float* A1 = sAm + (4 * g + 1) * 32;
        const float* A2 = sAm + (4 * g + 2) * 32;
        const float* A3 = sAm + (4 * g + 3) * 32;
        uint4 row[4];
        __half2* hp = (__half2*)row;
        #pragma unroll
        for (int k2 = 0; k2 < 16; ++k2) {
            float qa = x0 * A0[2 * k2];
            qa = fmaf(x1, A1[2 * k2], qa);
            qa = fmaf(x2, A2[2 * k2], qa);
            qa = fmaf(x3, A3[2 * k2], qa);
            float qb = x0 * A0[2 * k2 + 1];
            qb = fmaf(x1, A1[2 * k2 + 1], qb);
            qb = fmaf(x2, A2[2 * k2 + 1], qb);
            qb = fmaf(x3, A3[2 * k2 + 1], qb);
            hp[k2] = __floats2half2_rn(qa, qb);
        }
        uint4* dst = &smem[(g * 400 + t) * 5];
        dst[0] = row[0]; dst[1] = row[1]; dst[2] = row[2]; dst[3] = row[3];
    }
    __syncthreads();

    // ---- phase 3: this block's 25 unshuffled outputs ----
    if (tid < 25) {
        const int t = chunk * 25 + tid;
        float h1[32];
        #pragma unroll
        for (int k = 0; k < 32; ++k) h1[k] = sB1[k];
        #pragma unroll
        for (int g = 0; g < 4; ++g) {
            const __half* qr = (const __half*)&smem[(g * 400 + t) * 5];
            #pragma unroll
            for (int k = 0; k < 32; ++k) h1[k] += (float)qr[k];
        }
        #pragma unroll
        for (int k = 0; k < 32; ++k) h1[k] = fmaxf(h1[k], 0.01f * h1[k]);
        float h2[16];
        #pragma unroll
        for (int j = 0; j < 16; ++j) h2[j] = sB2[j];
        #pragma unroll
        for (int k = 0; k < 32; ++k) {
            const float a = h1[k];
            #pragma unroll
            for (int j = 0; j < 16; ++j) h2[j] = fmaf(a, sW2[k * 16 + j], h2[j]);
        }
        float acc = sB3;
        #pragma unroll
        for (int j = 0; j < 16; ++j) {
            const float hj = fmaxf(h2[j], 0.01f * h2[j]);
            acc = fmaf(hj, sW3[j], acc);
        }
        out[(size_t)s * OUT_ROW + t] = 1.f / (1.f + __expf(-acc));
    }

    // ---- phase 4: shuffled eval ----
    const int lane = tid & 63;
    const int wv   = tid >> 6;           // wave 0..15
    const int m    = lane & 15;          // sample-in-group (B col)
    const int c    = lane >> 4;          // k-chunk / quad

    f16x8 afrag, b1v;
    #pragma unroll
    for (int j = 0; j < 8; ++j) {
        afrag[j] = (_Float16)sW2[(c * 8 + j) * 16 + m];   // A = W2^T frag
        b1v[j]   = (_Float16)sB1[c * 8 + j];
    }
    const float4 b2v = *(const float4*)(sB2 + c * 4);
    const float4 w3v = *(const float4*)(sW3 + c * 4);
    const float  b3s = sB3;

    for (int tile = wv; tile < 98; tile += 16) {
        const int jt = j0b + tile * 64;

        // perm indices: lane (m,c) loads all 4 groups of its sample directly
        int idx[4][4];   // [q][g]
        #pragma unroll
        for (int q = 0; q < 4; ++q) {
            int j = jt + q * 16 + m;
            int jc = j0b + 6249;
            if (j < jc) jc = j;          // clamp (partial last tile)
            const int sf = jc / 400;
            const int t  = jc - sf * 400;
            const int pb = sf * 25600 + s * 400 + t;
            #pragma unroll
            for (int g = 0; g < 4; ++g)
                idx[q][g] = perm[pb + g * 6400];
        }

        float res0, res1, res2, res3;
        #pragma unroll
        for (int q = 0; q < 4; ++q) {
            QU a0, a1, a2, a3;
            a0.u = smem[(idx[q][0]        ) * 5 + c];
            a1.u = smem[( 400 + idx[q][1] ) * 5 + c];
            a2.u = smem[( 800 + idx[q][2] ) * 5 + c];
            a3.u = smem[(1200 + idx[q][3] ) * 5 + c];

            f16x8 h = (a0.v + a1.v) + (a2.v + a3.v) + b1v;
            #pragma unroll
            for (int k = 0; k < 8; ++k) {
                _Float16 x = h[k];
                _Float16 y = x * (_Float16)0.01f;
                h[k] = x > y ? x : y;    // leaky relu -> v_(pk_)max_f16
            }

            f32x4 acc = {0.f, 0.f, 0.f, 0.f};
            acc = __builtin_amdgcn_mfma_f32_16x16x32_f16(afrag, h, acc, 0, 0, 0);

            float p;
            {
                float v0 = acc[0] + b2v.x; v0 = fmaxf(v0, 0.01f * v0); p = v0 * w3v.x;
                float v1 = acc[1] + b2v.y; v1 = fmaxf(v1, 0.01f * v1); p = fmaf(v1, w3v.y, p);
                float v2 = acc[2] + b2v.z; v2 = fmaxf(v2, 0.01f * v2); p = fmaf(v2, w3v.z, p);
                float v3 = acc[3] + b2v.w; v3 = fmaxf(v3, 0.01f * v3); p = fmaf(v3, w3v.w, p);
            }
            p += __shfl_xor(p, 16);
            p += __shfl_xor(p, 32);
            if (q == 0) res0 = p;
            else if (q == 1) res1 = p;
            else if (q == 2) res2 = p;
            else res3 = p;
        }

        // lane l holds sample jt+l's value in res[c(l)] (round q == c)
        float v = res0;
        if (c == 1) v = res1;
        if (c == 2) v = res2;
        if (c == 3) v = res3;
        v += b3s;
        const float sg = 1.f / (1.f + __expf(-v));
        const int j = jt + lane;
        if (j < j0b + 6250)
            out[(size_t)s * OUT_ROW + 400 + j] = sg;
    }
}

extern "C" void kernel_launch(void* const* d_in, const int* in_sizes, int n_in,
                              void* d_out, int out_size, void* d_ws, size_t ws_size,
                              hipStream_t stream) {
    (void)in_sizes; (void)n_in; (void)out_size; (void)d_ws; (void)ws_size;
    const float* obs = (const float*)d_in[0];
    const float* mu  = (const float*)d_in[1];
    const float* Sig = (const float*)d_in[2];
    const int*   prm = (const int*)d_in[3];
    const float* W1  = (const float*)d_in[4];
    const float* b1  = (const float*)d_in[5];
    const float* W2  = (const float*)d_in[6];
    const float* b2  = (const float*)d_in[7];
    const float* W3  = (const float*)d_in[8];
    const float* b3  = (const float*)d_in[9];
    float* out = (float*)d_out;

    // allow >64 KiB dynamic LDS
    (void)hipFuncSetAttribute((const void*)fused_kernel,
                              hipFuncAttributeMaxDynamicSharedMemorySize,
                              LDS_U4 * 16);

    hipLaunchKernelGGL(fused_kernel, dim3(256), dim3(1024), LDS_U4 * 16, stream,
                       obs, mu, Sig, prm, W1, b1, W2, b2, W3, b3, out);
}